// Round 11
// baseline (393.178 us; speedup 1.0000x reference)
//
#include <hip/hip_runtime.h>
#include <hip/hip_fp16.h>
#include <math.h>

#define N_NODES 50000
#define N_EDGES 800000
#define IN_C 96
#define HID_C 64
#define OUT_C 40
#define ALPHA 0.2f
#define NEG_SLOPE 0.01f

typedef _Float16 f16x8 __attribute__((ext_vector_type(8)));
typedef float f32x4 __attribute__((ext_vector_type(4)));

__device__ __forceinline__ int edge_at(const void* ei, int is64, long long pos) {
    return is64 ? (int)((const long long*)ei)[pos] : ((const int*)ei)[pos];
}

// ---------------- zero deg + edge dtype detect (fused) ----------------
__global__ void zero_detect_k(int* deg, int n, const unsigned int* ei, int* flag) {
    int i = blockIdx.x * blockDim.x + threadIdx.x;
    if (i < n) deg[i] = 0;
    if (i == 0) {
        int is64 = 1;
        for (int j = 1; j < 16; j += 2)
            if (ei[j] != 0u) is64 = 0;
        *flag = is64;
    }
}

__global__ void deg_hist_k(const void* ei, const int* flag, int* deg, int E) {
    int e = blockIdx.x * blockDim.x + threadIdx.x;
    if (e < E) {
        int d = edge_at(ei, *flag, (long long)E + e);
        atomicAdd(&deg[d], 1);
    }
}

// ---- parallel 3-phase exclusive scan over deg[n] ----
__global__ void scan_p1_k(const int* __restrict__ deg, int* __restrict__ part, int n) {
    __shared__ int sm[256];
    int t = threadIdx.x, i = blockIdx.x * 256 + t;
    int v = (i < n) ? deg[i] : 0;
    sm[t] = v;
    __syncthreads();
    for (int off = 1; off < 256; off <<= 1) {
        int u = (t >= off) ? sm[t - off] : 0;
        __syncthreads();
        sm[t] += u;
        __syncthreads();
    }
    if (t == 255) part[blockIdx.x] = sm[255];
}

__global__ void scan_p2_k(int* part, int nb, int* rowptr, int n) {
    __shared__ int sm[256];
    int t = threadIdx.x;
    int v = (t < nb) ? part[t] : 0;
    sm[t] = v;
    __syncthreads();
    for (int off = 1; off < 256; off <<= 1) {
        int u = (t >= off) ? sm[t - off] : 0;
        __syncthreads();
        sm[t] += u;
        __syncthreads();
    }
    if (t < nb) part[t] = sm[t] - v;  // exclusive
    if (t == 255) rowptr[n] = sm[255];
}

__global__ void scan_p3_k(const int* __restrict__ deg, const int* __restrict__ part,
                          int* __restrict__ rowptr, int* __restrict__ cursor,
                          float* __restrict__ dinv, int n) {
    __shared__ int sm[256];
    int t = threadIdx.x, i = blockIdx.x * 256 + t;
    int v = (i < n) ? deg[i] : 0;
    sm[t] = v;
    __syncthreads();
    for (int off = 1; off < 256; off <<= 1) {
        int u = (t >= off) ? sm[t - off] : 0;
        __syncthreads();
        sm[t] += u;
        __syncthreads();
    }
    if (i < n) {
        int excl = sm[t] - v + part[blockIdx.x];
        rowptr[i] = excl;
        cursor[i] = excl;
        dinv[i] = rsqrtf((float)v + 1.0f);  // +1 self loop
    }
}

// ---- degree counting sort (descending) -> perm, hierarchical (LDS-only atomics)
// bucket b = 63 - min(deg,63): descending degree so heavy nodes lead the grid.
__global__ void bhist_k(const int* __restrict__ deg, int* __restrict__ bcnt, int n) {
    __shared__ int h[64];
    int t = threadIdx.x, i = blockIdx.x * 256 + t;
    if (t < 64) h[t] = 0;
    __syncthreads();
    if (i < n) {
        int d = deg[i]; if (d > 63) d = 63;
        atomicAdd(&h[63 - d], 1);
    }
    __syncthreads();
    if (t < 64) bcnt[blockIdx.x * 64 + t] = h[t];
}

// single wave: per-bucket totals over blocks, cross-bucket exclusive scan,
// then per-block bases.  nb <= 256 blocks.
__global__ void bscan_k(const int* __restrict__ bcnt, int* __restrict__ bbase, int nb) {
    __shared__ int tot[64];
    int b = threadIdx.x;  // 64 threads
    int s = 0;
    for (int j = 0; j < nb; ++j) s += bcnt[j * 64 + b];
    tot[b] = s;
    __syncthreads();
    if (b == 0) {
        int run = 0;
        for (int k = 0; k < 64; ++k) { int v = tot[k]; tot[k] = run; run += v; }
    }
    __syncthreads();
    int run = tot[b];
    for (int j = 0; j < nb; ++j) {
        bbase[j * 64 + b] = run;
        run += bcnt[j * 64 + b];
    }
}

__global__ void perm_k(const int* __restrict__ deg, const int* __restrict__ bbase,
                       int* __restrict__ perm, int n) {
    __shared__ int h[64];
    int t = threadIdx.x, i = blockIdx.x * 256 + t;
    if (t < 64) h[t] = 0;
    __syncthreads();
    if (i < n) {
        int d = deg[i]; if (d > 63) d = 63;
        int b = 63 - d;
        int rank = atomicAdd(&h[b], 1);
        perm[bbase[blockIdx.x * 64 + b] + rank] = i;
    }
}

// fill CSR, XCD-partitioned: blockIdx%8 owns dst range [p*N/8,(p+1)*N/8).
// 2 independent edge chains per thread iteration for MLP.
#define FILL_CHUNK 2048
__global__ void csr_fill_k(const void* ei, const int* flag,
                           int* __restrict__ cursor, int* __restrict__ csrc,
                           int E, int N) {
    int p = blockIdx.x & 7;
    int chunk = blockIdx.x >> 3;
    int lo = p * (N / 8), hi = lo + (N / 8);  // 50000/8 = 6250 exact
    int e0 = chunk * FILL_CHUNK;
    int e1 = e0 + FILL_CHUNK; if (e1 > E) e1 = E;
    int f = *flag;
    for (int e = e0 + threadIdx.x; e < e1; e += 2 * blockDim.x) {
        int e2 = e + blockDim.x;
        int d0 = edge_at(ei, f, (long long)E + e);
        int d1 = (e2 < e1) ? edge_at(ei, f, (long long)E + e2) : -1;
        if (d0 >= lo && d0 < hi) {
            int s = edge_at(ei, f, e);
            int pos = atomicAdd(&cursor[d0], 1);
            csrc[pos] = s;
        }
        if (d1 >= lo && d1 < hi) {
            int s = edge_at(ei, f, e2);
            int pos = atomicAdd(&cursor[d1], 1);
            csrc[pos] = s;
        }
    }
}

// ---------------- C=64 prop: quarter-wave per NODE (degree-sorted) -------------
// 16-lane QW owns one node (= perm[qw]): lane ci holds channels [4ci,4ci+4)
// end-to-end -> no reductions, no idle lanes; 4-deep unroll. Degree-sorted
// order makes the 4 QWs of a wave near-equal walk length.
template <bool COMBINE, bool LEAKY, bool BIAS>
__global__ void prop64_k(const int* __restrict__ perm,
                         const int* __restrict__ rowptr, const int* __restrict__ csrc,
                         const float* __restrict__ dinv,
                         const __half* __restrict__ in, const __half* __restrict__ h0,
                         const float* __restrict__ bias,
                         __half* __restrict__ out, int N) {
    int qw = blockIdx.x * (blockDim.x >> 4) + (threadIdx.x >> 4);
    int ci = threadIdx.x & 15;
    if (qw >= N) return;
    int node = perm[qw];
    const float2* in4 = (const float2*)in;  // 8 B = 4 halves (bit-carrier)
    f32x4 acc;
    {   // self-loop term G[node]
        float2 r = in4[node * 16 + ci];
        float2 a = __half22float2(*(const __half2*)&r.x);
        float2 b = __half22float2(*(const __half2*)&r.y);
        acc[0] = a.x; acc[1] = a.y; acc[2] = b.x; acc[3] = b.y;
    }
    int r0 = rowptr[node], r1 = rowptr[node + 1];
    int i = r0;
    for (; i + 3 < r1; i += 4) {  // 4 rows in flight per QW
        int s0 = csrc[i], s1 = csrc[i + 1], s2 = csrc[i + 2], s3 = csrc[i + 3];
        float2 v0 = in4[s0 * 16 + ci];
        float2 v1 = in4[s1 * 16 + ci];
        float2 v2 = in4[s2 * 16 + ci];
        float2 v3 = in4[s3 * 16 + ci];
        float2 a0 = __half22float2(*(const __half2*)&v0.x), b0 = __half22float2(*(const __half2*)&v0.y);
        float2 a1 = __half22float2(*(const __half2*)&v1.x), b1 = __half22float2(*(const __half2*)&v1.y);
        float2 a2 = __half22float2(*(const __half2*)&v2.x), b2 = __half22float2(*(const __half2*)&v2.y);
        float2 a3 = __half22float2(*(const __half2*)&v3.x), b3 = __half22float2(*(const __half2*)&v3.y);
        acc[0] += (a0.x + a1.x) + (a2.x + a3.x);
        acc[1] += (a0.y + a1.y) + (a2.y + a3.y);
        acc[2] += (b0.x + b1.x) + (b2.x + b3.x);
        acc[3] += (b0.y + b1.y) + (b2.y + b3.y);
    }
    for (; i < r1; ++i) {
        float2 v0 = in4[csrc[i] * 16 + ci];
        float2 a0 = __half22float2(*(const __half2*)&v0.x), b0 = __half22float2(*(const __half2*)&v0.y);
        acc[0] += a0.x; acc[1] += a0.y; acc[2] += b0.x; acc[3] += b0.y;
    }
    float di = dinv[node];
    float sc = di * di;
    float4 v;
    v.x = sc * acc[0]; v.y = sc * acc[1]; v.z = sc * acc[2]; v.w = sc * acc[3];
    if (BIAS) {
        const float4 b = ((const float4*)bias)[ci];
        v.x += di * b.x; v.y += di * b.y; v.z += di * b.z; v.w += di * b.w;
    }
    if (COMBINE) {
        float2 r = ((const float2*)h0)[node * 16 + ci];
        float2 a = __half22float2(*(const __half2*)&r.x);
        float2 b = __half22float2(*(const __half2*)&r.y);
        v.x = (1.0f - ALPHA) * v.x + ALPHA * a.x;
        v.y = (1.0f - ALPHA) * v.y + ALPHA * a.y;
        v.z = (1.0f - ALPHA) * v.z + ALPHA * b.x;
        v.w = (1.0f - ALPHA) * v.w + ALPHA * b.y;
    }
    if (LEAKY) {
        v.x = v.x > 0.0f ? v.x : NEG_SLOPE * v.x;
        v.y = v.y > 0.0f ? v.y : NEG_SLOPE * v.y;
        v.z = v.z > 0.0f ? v.z : NEG_SLOPE * v.z;
        v.w = v.w > 0.0f ? v.w : NEG_SLOPE * v.w;
    }
    float2 o;
    *(__half2*)&o.x = __float22half2_rn(make_float2(v.x, v.y));
    *(__half2*)&o.y = __float22half2_rn(make_float2(v.z, v.w));
    ((float2*)out)[node * 16 + ci] = o;
}

// ---------------- C=40 prop: half-wave per NODE (degree-sorted) ----------------
__global__ void prop40_k(const int* __restrict__ perm,
                         const int* __restrict__ rowptr, const int* __restrict__ csrc,
                         const float* __restrict__ dinv,
                         const __half* __restrict__ in, __half* __restrict__ out, int N) {
    constexpr int CP = OUT_C / 2;  // 20
    int hw = blockIdx.x * (blockDim.x >> 5) + (threadIdx.x >> 5);
    int ci = threadIdx.x & 31;
    if (hw >= N) return;
    int node = perm[hw];
    bool act = ci < CP;
    const __half2* in2 = (const __half2*)in;
    float2 acc = make_float2(0.0f, 0.0f);
    if (act) {
        acc = __half22float2(in2[(long long)node * CP + ci]);
    }
    int r0 = rowptr[node], r1 = rowptr[node + 1];
    int i = r0;
    for (; i + 3 < r1; i += 4) {
        int s0 = csrc[i], s1 = csrc[i + 1], s2 = csrc[i + 2], s3 = csrc[i + 3];
        if (act) {
            float2 v0 = __half22float2(in2[(long long)s0 * CP + ci]);
            float2 v1 = __half22float2(in2[(long long)s1 * CP + ci]);
            float2 v2 = __half22float2(in2[(long long)s2 * CP + ci]);
            float2 v3 = __half22float2(in2[(long long)s3 * CP + ci]);
            acc.x += (v0.x + v1.x) + (v2.x + v3.x);
            acc.y += (v0.y + v1.y) + (v2.y + v3.y);
        }
    }
    for (; i < r1; ++i) {
        int s0 = csrc[i];
        if (act) {
            float2 v0 = __half22float2(in2[(long long)s0 * CP + ci]);
            acc.x += v0.x; acc.y += v0.y;
        }
    }
    if (act) {
        float di = dinv[node];
        float sc = di * di;
        ((__half2*)out)[(long long)node * CP + ci] =
            __float22half2_rn(make_float2(sc * acc.x, sc * acc.y));
    }
}

// ---------------- final C=40 prop + b4 + log_softmax fused, fp32 out -----------
__global__ void prop40_softmax_k(const int* __restrict__ perm,
                                 const int* __restrict__ rowptr, const int* __restrict__ csrc,
                                 const float* __restrict__ dinv,
                                 const __half* __restrict__ in, const float* __restrict__ bias,
                                 float* __restrict__ out, int N) {
    constexpr int CP = OUT_C / 2;  // 20
    int hw = blockIdx.x * (blockDim.x >> 5) + (threadIdx.x >> 5);
    int ci = threadIdx.x & 31;
    if (hw >= N) return;
    int node = perm[hw];
    bool act = ci < CP;
    const __half2* in2 = (const __half2*)in;
    float2 acc = make_float2(0.0f, 0.0f);
    if (act) {
        acc = __half22float2(in2[(long long)node * CP + ci]);
    }
    int r0 = rowptr[node], r1 = rowptr[node + 1];
    int i = r0;
    for (; i + 3 < r1; i += 4) {
        int s0 = csrc[i], s1 = csrc[i + 1], s2 = csrc[i + 2], s3 = csrc[i + 3];
        if (act) {
            float2 v0 = __half22float2(in2[(long long)s0 * CP + ci]);
            float2 v1 = __half22float2(in2[(long long)s1 * CP + ci]);
            float2 v2 = __half22float2(in2[(long long)s2 * CP + ci]);
            float2 v3 = __half22float2(in2[(long long)s3 * CP + ci]);
            acc.x += (v0.x + v1.x) + (v2.x + v3.x);
            acc.y += (v0.y + v1.y) + (v2.y + v3.y);
        }
    }
    for (; i < r1; ++i) {
        int s0 = csrc[i];
        if (act) {
            float2 v0 = __half22float2(in2[(long long)s0 * CP + ci]);
            acc.x += v0.x; acc.y += v0.y;
        }
    }
    float di = dinv[node];
    float2 v = make_float2(-INFINITY, -INFINITY);
    if (act) {
        v.x = di * acc.x + bias[2 * ci];
        v.y = di * acc.y + bias[2 * ci + 1];
    }
    float m = fmaxf(v.x, v.y);
    #pragma unroll
    for (int off = 16; off >= 1; off >>= 1) m = fmaxf(m, __shfl_xor(m, off));
    float e = act ? (expf(v.x - m) + expf(v.y - m)) : 0.0f;
    #pragma unroll
    for (int off = 16; off >= 1; off >>= 1) e += __shfl_xor(e, off);
    float ls = m + logf(e);
    if (act)
        ((float2*)out)[(long long)node * CP + ci] = make_float2(v.x - ls, v.y - ls);
}

// ---------------- MFMA dense linear: out[m,o] = sum_k in[m,k]*W[o,k] -----------
template <int O, int K, bool FP32IN, bool SCALE>
__global__ void __launch_bounds__(256) mfma_lin_k(const void* __restrict__ in_,
                                                  const float* __restrict__ W,
                                                  const float* __restrict__ dinv,
                                                  __half* __restrict__ out, int Mtiles) {
    constexpr int P2 = 52;  // half2 pitch (104 halves = 208 B rows, 16B-aligned)
    __shared__ __half2 wsh[O * P2];
    for (int idx = threadIdx.x; idx < O * (K / 2); idx += 256) {
        int o = idx / (K / 2), kk = idx - o * (K / 2);
        float2 w2 = ((const float2*)W)[o * (K / 2) + kk];
        wsh[o * P2 + kk] = __floats2half2_rn(w2.x, w2.y);
    }
    __syncthreads();
    int wave = (blockIdx.x * 256 + threadIdx.x) >> 6;
    if (wave >= Mtiles) return;
    int lane = threadIdx.x & 63;
    int lm = lane & 15, q = lane >> 4;
    long long m0 = (long long)wave * 16;
    constexpr int NT = (O + 15) / 16;
    f32x4 acc[NT];
    #pragma unroll
    for (int j = 0; j < NT; ++j) acc[j] = (f32x4){0.f, 0.f, 0.f, 0.f};
    const __half* wsp = (const __half*)wsh;
    #pragma unroll
    for (int k0 = 0; k0 < K; k0 += 32) {
        f16x8 a;
        if (FP32IN) {
            const float* xr = (const float*)in_ + (m0 + lm) * K + k0 + q * 8;
            float4 x0 = ((const float4*)xr)[0];
            float4 x1 = ((const float4*)xr)[1];
            a = (f16x8){(_Float16)x0.x, (_Float16)x0.y, (_Float16)x0.z, (_Float16)x0.w,
                        (_Float16)x1.x, (_Float16)x1.y, (_Float16)x1.z, (_Float16)x1.w};
        } else {
            const __half* xr = (const __half*)in_ + (m0 + lm) * K + k0 + q * 8;
            a = *(const f16x8*)xr;
        }
        #pragma unroll
        for (int j = 0; j < NT; ++j) {
            f16x8 b = *(const f16x8*)(wsp + (16 * j + lm) * (2 * P2) + k0 + q * 8);
            acc[j] = __builtin_amdgcn_mfma_f32_16x16x32_f16(a, b, acc[j], 0, 0, 0);
        }
    }
    #pragma unroll
    for (int r = 0; r < 4; ++r) {
        long long m = m0 + q * 4 + r;
        float sc = SCALE ? dinv[m] : 1.0f;
        #pragma unroll
        for (int j = 0; j < NT; ++j) {
            int col = 16 * j + lm;
            if (col < O) out[m * O + col] = __float2half(acc[j][r] * sc);
        }
    }
}

// ---------------- launcher ----------------
static inline int cdiv(long long a, long long b) { return (int)((a + b - 1) / b); }
static inline size_t align256(size_t x) { return (x + 255) & ~(size_t)255; }

extern "C" void kernel_launch(void* const* d_in, const int* in_sizes, int n_in,
                              void* d_out, int out_size, void* d_ws, size_t ws_size,
                              hipStream_t stream) {
    const float* x  = (const float*)d_in[0];
    const void*  ei = d_in[1];
    const float* W0 = (const float*)d_in[2];
    const float* b0 = (const float*)d_in[3];
    const float* W4 = (const float*)d_in[4];
    const float* b4 = (const float*)d_in[5];
    float* out = (float*)d_out;

    const int N = N_NODES, E = N_EDGES;
    const int NB = cdiv(N, 256);  // 196
    char* ws = (char*)d_ws;
    int*    flag   = (int*)ws;     ws += 256;
    int*    deg    = (int*)ws;     ws += align256((size_t)N * 4);
    int*    rowptr = (int*)ws;     ws += align256((size_t)(N + 1) * 4);
    int*    cursor = (int*)ws;     ws += align256((size_t)N * 4);
    int*    part   = (int*)ws;     ws += align256(256 * 4);
    int*    bcnt   = (int*)ws;     ws += align256((size_t)NB * 64 * 4);
    int*    bbase  = (int*)ws;     ws += align256((size_t)NB * 64 * 4);
    int*    perm   = (int*)ws;     ws += align256((size_t)N * 4);
    float*  dinv   = (float*)ws;   ws += align256((size_t)N * 4);
    int*    csrc   = (int*)ws;     ws += align256((size_t)E * 4);
    __half* bufA   = (__half*)ws;  ws += align256((size_t)N * HID_C * 2);
    __half* bufB   = (__half*)ws;  ws += align256((size_t)N * HID_C * 2);
    __half* bufC   = (__half*)ws;  ws += align256((size_t)N * HID_C * 2);

    const int T = 256;
    const int MT = N / 16;             // 3125 MFMA tiles
    const int LB = cdiv(MT, 4);        // mfma_lin blocks (4 waves each)
    const int P64B = cdiv(N, T / 16);  // prop64 blocks (16 QWs each)
    const int P40B = cdiv(N, T / 32);  // prop40 blocks (8 HWs each)

    // ---- CSR build + degree sort ----
    zero_detect_k<<<cdiv(N, T), T, 0, stream>>>(deg, N, (const unsigned int*)ei, flag);
    deg_hist_k<<<cdiv(E, T), T, 0, stream>>>(ei, flag, deg, E);
    scan_p1_k<<<NB, 256, 0, stream>>>(deg, part, N);
    scan_p2_k<<<1, 256, 0, stream>>>(part, NB, rowptr, N);
    scan_p3_k<<<NB, 256, 0, stream>>>(deg, part, rowptr, cursor, dinv, N);
    bhist_k<<<NB, 256, 0, stream>>>(deg, bcnt, N);
    bscan_k<<<1, 64, 0, stream>>>(bcnt, bbase, NB);
    perm_k<<<NB, 256, 0, stream>>>(deg, bbase, perm, N);
    csr_fill_k<<<cdiv(E, FILL_CHUNK) * 8, T, 0, stream>>>(ei, flag, cursor, csrc, E, N);

    // ---- conv0 (SGConv, K=2): linear folded first; output G-space ----
    mfma_lin_k<HID_C, IN_C, true, true><<<LB, 256, 0, stream>>>(x, W0, dinv, bufA, MT);
    prop64_k<false, false, false><<<P64B, T, 0, stream>>>(
        perm, rowptr, csrc, dinv, bufA, nullptr, nullptr, bufB, N);
    prop64_k<false, false, true><<<P64B, T, 0, stream>>>(
        perm, rowptr, csrc, dinv, bufB, nullptr, b0, bufC, N);  // + dinv*b0 -> Gh0

    // ---- conv1..conv3: leaky(APPNP(h)) entirely in G-space, Gh0 = bufC ----
    for (int r = 0; r < 3; ++r) {
        prop64_k<true, false, false><<<P64B, T, 0, stream>>>(
            perm, rowptr, csrc, dinv, bufC, bufC, nullptr, bufB, N);
        // in-place bufC write safe: Gh0[node] read only by the QW writing it
        prop64_k<true, true, false><<<P64B, T, 0, stream>>>(
            perm, rowptr, csrc, dinv, bufB, bufC, nullptr, bufC, N);
    }

    // ---- conv4 (SGConv, K=2): G-space lin (no scale), then 2 hops at 40ch ----
    mfma_lin_k<OUT_C, HID_C, false, false><<<LB, 256, 0, stream>>>(bufC, W4, dinv, bufA, MT);
    prop40_k<<<P40B, T, 0, stream>>>(perm, rowptr, csrc, dinv, bufA, bufB, N);
    prop40_softmax_k<<<P40B, T, 0, stream>>>(perm, rowptr, csrc, dinv, bufB, b4, out, N);
}

// Round 12
// 352.637 us; speedup vs baseline: 1.1150x; 1.1150x over previous
//
#include <hip/hip_runtime.h>
#include <hip/hip_fp16.h>
#include <math.h>

#define N_NODES 50000
#define N_EDGES 800000
#define IN_C 96
#define HID_C 64
#define OUT_C 40
#define ALPHA 0.2f
#define NEG_SLOPE 0.01f

typedef _Float16 f16x8 __attribute__((ext_vector_type(8)));
typedef float f32x4 __attribute__((ext_vector_type(4)));

__device__ __forceinline__ int edge_at(const void* ei, int is64, long long pos) {
    return is64 ? (int)((const long long*)ei)[pos] : ((const int*)ei)[pos];
}

// ---------------- zero deg + edge dtype detect (fused) ----------------
__global__ void zero_detect_k(int* deg, int n, const unsigned int* ei, int* flag) {
    int i = blockIdx.x * blockDim.x + threadIdx.x;
    if (i < n) deg[i] = 0;
    if (i == 0) {
        int is64 = 1;
        for (int j = 1; j < 16; j += 2)
            if (ei[j] != 0u) is64 = 0;
        *flag = is64;
    }
}

__global__ void deg_hist_k(const void* ei, const int* flag, int* deg, int E) {
    int e = blockIdx.x * blockDim.x + threadIdx.x;
    if (e < E) {
        int d = edge_at(ei, *flag, (long long)E + e);
        atomicAdd(&deg[d], 1);
    }
}

// ---- parallel 3-phase exclusive scan over deg[n] ----
__global__ void scan_p1_k(const int* __restrict__ deg, int* __restrict__ part, int n) {
    __shared__ int sm[256];
    int t = threadIdx.x, i = blockIdx.x * 256 + t;
    int v = (i < n) ? deg[i] : 0;
    sm[t] = v;
    __syncthreads();
    for (int off = 1; off < 256; off <<= 1) {
        int u = (t >= off) ? sm[t - off] : 0;
        __syncthreads();
        sm[t] += u;
        __syncthreads();
    }
    if (t == 255) part[blockIdx.x] = sm[255];
}

__global__ void scan_p2_k(int* part, int nb, int* rowptr, int n) {
    __shared__ int sm[256];
    int t = threadIdx.x;
    int v = (t < nb) ? part[t] : 0;
    sm[t] = v;
    __syncthreads();
    for (int off = 1; off < 256; off <<= 1) {
        int u = (t >= off) ? sm[t - off] : 0;
        __syncthreads();
        sm[t] += u;
        __syncthreads();
    }
    if (t < nb) part[t] = sm[t] - v;  // exclusive
    if (t == 255) rowptr[n] = sm[255];
}

__global__ void scan_p3_k(const int* __restrict__ deg, const int* __restrict__ part,
                          int* __restrict__ rowptr, int* __restrict__ cursor,
                          float* __restrict__ dinv, int n) {
    __shared__ int sm[256];
    int t = threadIdx.x, i = blockIdx.x * 256 + t;
    int v = (i < n) ? deg[i] : 0;
    sm[t] = v;
    __syncthreads();
    for (int off = 1; off < 256; off <<= 1) {
        int u = (t >= off) ? sm[t - off] : 0;
        __syncthreads();
        sm[t] += u;
        __syncthreads();
    }
    if (i < n) {
        int excl = sm[t] - v + part[blockIdx.x];
        rowptr[i] = excl;
        cursor[i] = excl;
        dinv[i] = rsqrtf((float)v + 1.0f);  // +1 self loop
    }
}

// ---- degree counting sort (descending) -> perm, hierarchical (LDS-only atomics)
// bucket b = 63 - min(deg,63): descending degree so heavy nodes lead the grid.
__global__ void bhist_k(const int* __restrict__ deg, int* __restrict__ bcnt, int n) {
    __shared__ int h[64];
    int t = threadIdx.x, i = blockIdx.x * 256 + t;
    if (t < 64) h[t] = 0;
    __syncthreads();
    if (i < n) {
        int d = deg[i]; if (d > 63) d = 63;
        atomicAdd(&h[63 - d], 1);
    }
    __syncthreads();
    if (t < 64) bcnt[blockIdx.x * 64 + t] = h[t];
}

// bscanA: one block per bucket; parallel exclusive scan over nb block-counts.
// Writes local (per-bucket) exclusive bases and the bucket total.
__global__ void bscanA_k(const int* __restrict__ bcnt, int* __restrict__ bbase,
                         int* __restrict__ tot, int nb) {
    __shared__ int sm[256];
    int b = blockIdx.x;   // bucket
    int t = threadIdx.x;  // block index within bucket
    int v = (t < nb) ? bcnt[t * 64 + b] : 0;
    sm[t] = v;
    __syncthreads();
    for (int off = 1; off < 256; off <<= 1) {
        int u = (t >= off) ? sm[t - off] : 0;
        __syncthreads();
        sm[t] += u;
        __syncthreads();
    }
    if (t < nb) bbase[t * 64 + b] = sm[t] - v;  // exclusive, no bucket offset
    if (t == 255) tot[b] = sm[255];
}

// bscanB: single 64-thread block; exclusive scan of bucket totals -> starts.
__global__ void bscanB_k(const int* __restrict__ tot, int* __restrict__ bstart) {
    __shared__ int sm[64];
    int t = threadIdx.x;
    int v = tot[t];
    sm[t] = v;
    __syncthreads();
    for (int off = 1; off < 64; off <<= 1) {
        int u = (t >= off) ? sm[t - off] : 0;
        __syncthreads();
        sm[t] += u;
        __syncthreads();
    }
    bstart[t] = sm[t] - v;  // exclusive
}

__global__ void perm_k(const int* __restrict__ deg, const int* __restrict__ bbase,
                       const int* __restrict__ bstart, int* __restrict__ perm, int n) {
    __shared__ int h[64];
    int t = threadIdx.x, i = blockIdx.x * 256 + t;
    if (t < 64) h[t] = 0;
    __syncthreads();
    if (i < n) {
        int d = deg[i]; if (d > 63) d = 63;
        int b = 63 - d;
        int rank = atomicAdd(&h[b], 1);
        perm[bstart[b] + bbase[blockIdx.x * 64 + b] + rank] = i;
    }
}

// fill CSR, XCD-partitioned: blockIdx%8 owns dst range [p*N/8,(p+1)*N/8).
// 2 independent edge chains per thread iteration for MLP.
#define FILL_CHUNK 2048
__global__ void csr_fill_k(const void* ei, const int* flag,
                           int* __restrict__ cursor, int* __restrict__ csrc,
                           int E, int N) {
    int p = blockIdx.x & 7;
    int chunk = blockIdx.x >> 3;
    int lo = p * (N / 8), hi = lo + (N / 8);  // 50000/8 = 6250 exact
    int e0 = chunk * FILL_CHUNK;
    int e1 = e0 + FILL_CHUNK; if (e1 > E) e1 = E;
    int f = *flag;
    for (int e = e0 + threadIdx.x; e < e1; e += 2 * blockDim.x) {
        int e2 = e + blockDim.x;
        int d0 = edge_at(ei, f, (long long)E + e);
        int d1 = (e2 < e1) ? edge_at(ei, f, (long long)E + e2) : -1;
        if (d0 >= lo && d0 < hi) {
            int s = edge_at(ei, f, e);
            int pos = atomicAdd(&cursor[d0], 1);
            csrc[pos] = s;
        }
        if (d1 >= lo && d1 < hi) {
            int s = edge_at(ei, f, e2);
            int pos = atomicAdd(&cursor[d1], 1);
            csrc[pos] = s;
        }
    }
}

// ---------------- C=64 prop: quarter-wave per NODE (degree-sorted) -------------
// 16-lane QW owns one node (= perm[qw]): lane ci holds channels [4ci,4ci+4)
// end-to-end -> no reductions, no idle lanes; 4-deep unroll. Degree-sorted
// order makes the 4 QWs of a wave near-equal walk length.
template <bool COMBINE, bool LEAKY, bool BIAS>
__global__ void prop64_k(const int* __restrict__ perm,
                         const int* __restrict__ rowptr, const int* __restrict__ csrc,
                         const float* __restrict__ dinv,
                         const __half* __restrict__ in, const __half* __restrict__ h0,
                         const float* __restrict__ bias,
                         __half* __restrict__ out, int N) {
    int qw = blockIdx.x * (blockDim.x >> 4) + (threadIdx.x >> 4);
    int ci = threadIdx.x & 15;
    if (qw >= N) return;
    int node = perm[qw];
    const float2* in4 = (const float2*)in;  // 8 B = 4 halves (bit-carrier)
    f32x4 acc;
    {   // self-loop term G[node]
        float2 r = in4[node * 16 + ci];
        float2 a = __half22float2(*(const __half2*)&r.x);
        float2 b = __half22float2(*(const __half2*)&r.y);
        acc[0] = a.x; acc[1] = a.y; acc[2] = b.x; acc[3] = b.y;
    }
    int r0 = rowptr[node], r1 = rowptr[node + 1];
    int i = r0;
    for (; i + 3 < r1; i += 4) {  // 4 rows in flight per QW
        int s0 = csrc[i], s1 = csrc[i + 1], s2 = csrc[i + 2], s3 = csrc[i + 3];
        float2 v0 = in4[s0 * 16 + ci];
        float2 v1 = in4[s1 * 16 + ci];
        float2 v2 = in4[s2 * 16 + ci];
        float2 v3 = in4[s3 * 16 + ci];
        float2 a0 = __half22float2(*(const __half2*)&v0.x), b0 = __half22float2(*(const __half2*)&v0.y);
        float2 a1 = __half22float2(*(const __half2*)&v1.x), b1 = __half22float2(*(const __half2*)&v1.y);
        float2 a2 = __half22float2(*(const __half2*)&v2.x), b2 = __half22float2(*(const __half2*)&v2.y);
        float2 a3 = __half22float2(*(const __half2*)&v3.x), b3 = __half22float2(*(const __half2*)&v3.y);
        acc[0] += (a0.x + a1.x) + (a2.x + a3.x);
        acc[1] += (a0.y + a1.y) + (a2.y + a3.y);
        acc[2] += (b0.x + b1.x) + (b2.x + b3.x);
        acc[3] += (b0.y + b1.y) + (b2.y + b3.y);
    }
    for (; i < r1; ++i) {
        float2 v0 = in4[csrc[i] * 16 + ci];
        float2 a0 = __half22float2(*(const __half2*)&v0.x), b0 = __half22float2(*(const __half2*)&v0.y);
        acc[0] += a0.x; acc[1] += a0.y; acc[2] += b0.x; acc[3] += b0.y;
    }
    float di = dinv[node];
    float sc = di * di;
    float4 v;
    v.x = sc * acc[0]; v.y = sc * acc[1]; v.z = sc * acc[2]; v.w = sc * acc[3];
    if (BIAS) {
        const float4 b = ((const float4*)bias)[ci];
        v.x += di * b.x; v.y += di * b.y; v.z += di * b.z; v.w += di * b.w;
    }
    if (COMBINE) {
        float2 r = ((const float2*)h0)[node * 16 + ci];
        float2 a = __half22float2(*(const __half2*)&r.x);
        float2 b = __half22float2(*(const __half2*)&r.y);
        v.x = (1.0f - ALPHA) * v.x + ALPHA * a.x;
        v.y = (1.0f - ALPHA) * v.y + ALPHA * a.y;
        v.z = (1.0f - ALPHA) * v.z + ALPHA * b.x;
        v.w = (1.0f - ALPHA) * v.w + ALPHA * b.y;
    }
    if (LEAKY) {
        v.x = v.x > 0.0f ? v.x : NEG_SLOPE * v.x;
        v.y = v.y > 0.0f ? v.y : NEG_SLOPE * v.y;
        v.z = v.z > 0.0f ? v.z : NEG_SLOPE * v.z;
        v.w = v.w > 0.0f ? v.w : NEG_SLOPE * v.w;
    }
    float2 o;
    *(__half2*)&o.x = __float22half2_rn(make_float2(v.x, v.y));
    *(__half2*)&o.y = __float22half2_rn(make_float2(v.z, v.w));
    ((float2*)out)[node * 16 + ci] = o;
}

// ---------------- C=40 prop: half-wave per NODE (degree-sorted) ----------------
__global__ void prop40_k(const int* __restrict__ perm,
                         const int* __restrict__ rowptr, const int* __restrict__ csrc,
                         const float* __restrict__ dinv,
                         const __half* __restrict__ in, __half* __restrict__ out, int N) {
    constexpr int CP = OUT_C / 2;  // 20
    int hw = blockIdx.x * (blockDim.x >> 5) + (threadIdx.x >> 5);
    int ci = threadIdx.x & 31;
    if (hw >= N) return;
    int node = perm[hw];
    bool act = ci < CP;
    const __half2* in2 = (const __half2*)in;
    float2 acc = make_float2(0.0f, 0.0f);
    if (act) {
        acc = __half22float2(in2[(long long)node * CP + ci]);
    }
    int r0 = rowptr[node], r1 = rowptr[node + 1];
    int i = r0;
    for (; i + 3 < r1; i += 4) {
        int s0 = csrc[i], s1 = csrc[i + 1], s2 = csrc[i + 2], s3 = csrc[i + 3];
        if (act) {
            float2 v0 = __half22float2(in2[(long long)s0 * CP + ci]);
            float2 v1 = __half22float2(in2[(long long)s1 * CP + ci]);
            float2 v2 = __half22float2(in2[(long long)s2 * CP + ci]);
            float2 v3 = __half22float2(in2[(long long)s3 * CP + ci]);
            acc.x += (v0.x + v1.x) + (v2.x + v3.x);
            acc.y += (v0.y + v1.y) + (v2.y + v3.y);
        }
    }
    for (; i < r1; ++i) {
        int s0 = csrc[i];
        if (act) {
            float2 v0 = __half22float2(in2[(long long)s0 * CP + ci]);
            acc.x += v0.x; acc.y += v0.y;
        }
    }
    if (act) {
        float di = dinv[node];
        float sc = di * di;
        ((__half2*)out)[(long long)node * CP + ci] =
            __float22half2_rn(make_float2(sc * acc.x, sc * acc.y));
    }
}

// ---------------- final C=40 prop + b4 + log_softmax fused, fp32 out -----------
__global__ void prop40_softmax_k(const int* __restrict__ perm,
                                 const int* __restrict__ rowptr, const int* __restrict__ csrc,
                                 const float* __restrict__ dinv,
                                 const __half* __restrict__ in, const float* __restrict__ bias,
                                 float* __restrict__ out, int N) {
    constexpr int CP = OUT_C / 2;  // 20
    int hw = blockIdx.x * (blockDim.x >> 5) + (threadIdx.x >> 5);
    int ci = threadIdx.x & 31;
    if (hw >= N) return;
    int node = perm[hw];
    bool act = ci < CP;
    const __half2* in2 = (const __half2*)in;
    float2 acc = make_float2(0.0f, 0.0f);
    if (act) {
        acc = __half22float2(in2[(long long)node * CP + ci]);
    }
    int r0 = rowptr[node], r1 = rowptr[node + 1];
    int i = r0;
    for (; i + 3 < r1; i += 4) {
        int s0 = csrc[i], s1 = csrc[i + 1], s2 = csrc[i + 2], s3 = csrc[i + 3];
        if (act) {
            float2 v0 = __half22float2(in2[(long long)s0 * CP + ci]);
            float2 v1 = __half22float2(in2[(long long)s1 * CP + ci]);
            float2 v2 = __half22float2(in2[(long long)s2 * CP + ci]);
            float2 v3 = __half22float2(in2[(long long)s3 * CP + ci]);
            acc.x += (v0.x + v1.x) + (v2.x + v3.x);
            acc.y += (v0.y + v1.y) + (v2.y + v3.y);
        }
    }
    for (; i < r1; ++i) {
        int s0 = csrc[i];
        if (act) {
            float2 v0 = __half22float2(in2[(long long)s0 * CP + ci]);
            acc.x += v0.x; acc.y += v0.y;
        }
    }
    float di = dinv[node];
    float2 v = make_float2(-INFINITY, -INFINITY);
    if (act) {
        v.x = di * acc.x + bias[2 * ci];
        v.y = di * acc.y + bias[2 * ci + 1];
    }
    float m = fmaxf(v.x, v.y);
    #pragma unroll
    for (int off = 16; off >= 1; off >>= 1) m = fmaxf(m, __shfl_xor(m, off));
    float e = act ? (expf(v.x - m) + expf(v.y - m)) : 0.0f;
    #pragma unroll
    for (int off = 16; off >= 1; off >>= 1) e += __shfl_xor(e, off);
    float ls = m + logf(e);
    if (act)
        ((float2*)out)[(long long)node * CP + ci] = make_float2(v.x - ls, v.y - ls);
}

// ---------------- MFMA dense linear: out[m,o] = sum_k in[m,k]*W[o,k] -----------
template <int O, int K, bool FP32IN, bool SCALE>
__global__ void __launch_bounds__(256) mfma_lin_k(const void* __restrict__ in_,
                                                  const float* __restrict__ W,
                                                  const float* __restrict__ dinv,
                                                  __half* __restrict__ out, int Mtiles) {
    constexpr int P2 = 52;  // half2 pitch (104 halves = 208 B rows, 16B-aligned)
    __shared__ __half2 wsh[O * P2];
    for (int idx = threadIdx.x; idx < O * (K / 2); idx += 256) {
        int o = idx / (K / 2), kk = idx - o * (K / 2);
        float2 w2 = ((const float2*)W)[o * (K / 2) + kk];
        wsh[o * P2 + kk] = __floats2half2_rn(w2.x, w2.y);
    }
    __syncthreads();
    int wave = (blockIdx.x * 256 + threadIdx.x) >> 6;
    if (wave >= Mtiles) return;
    int lane = threadIdx.x & 63;
    int lm = lane & 15, q = lane >> 4;
    long long m0 = (long long)wave * 16;
    constexpr int NT = (O + 15) / 16;
    f32x4 acc[NT];
    #pragma unroll
    for (int j = 0; j < NT; ++j) acc[j] = (f32x4){0.f, 0.f, 0.f, 0.f};
    const __half* wsp = (const __half*)wsh;
    #pragma unroll
    for (int k0 = 0; k0 < K; k0 += 32) {
        f16x8 a;
        if (FP32IN) {
            const float* xr = (const float*)in_ + (m0 + lm) * K + k0 + q * 8;
            float4 x0 = ((const float4*)xr)[0];
            float4 x1 = ((const float4*)xr)[1];
            a = (f16x8){(_Float16)x0.x, (_Float16)x0.y, (_Float16)x0.z, (_Float16)x0.w,
                        (_Float16)x1.x, (_Float16)x1.y, (_Float16)x1.z, (_Float16)x1.w};
        } else {
            const __half* xr = (const __half*)in_ + (m0 + lm) * K + k0 + q * 8;
            a = *(const f16x8*)xr;
        }
        #pragma unroll
        for (int j = 0; j < NT; ++j) {
            f16x8 b = *(const f16x8*)(wsp + (16 * j + lm) * (2 * P2) + k0 + q * 8);
            acc[j] = __builtin_amdgcn_mfma_f32_16x16x32_f16(a, b, acc[j], 0, 0, 0);
        }
    }
    #pragma unroll
    for (int r = 0; r < 4; ++r) {
        long long m = m0 + q * 4 + r;
        float sc = SCALE ? dinv[m] : 1.0f;
        #pragma unroll
        for (int j = 0; j < NT; ++j) {
            int col = 16 * j + lm;
            if (col < O) out[m * O + col] = __float2half(acc[j][r] * sc);
        }
    }
}

// ---------------- launcher ----------------
static inline int cdiv(long long a, long long b) { return (int)((a + b - 1) / b); }
static inline size_t align256(size_t x) { return (x + 255) & ~(size_t)255; }

extern "C" void kernel_launch(void* const* d_in, const int* in_sizes, int n_in,
                              void* d_out, int out_size, void* d_ws, size_t ws_size,
                              hipStream_t stream) {
    const float* x  = (const float*)d_in[0];
    const void*  ei = d_in[1];
    const float* W0 = (const float*)d_in[2];
    const float* b0 = (const float*)d_in[3];
    const float* W4 = (const float*)d_in[4];
    const float* b4 = (const float*)d_in[5];
    float* out = (float*)d_out;

    const int N = N_NODES, E = N_EDGES;
    const int NB = cdiv(N, 256);  // 196
    char* ws = (char*)d_ws;
    int*    flag   = (int*)ws;     ws += 256;
    int*    deg    = (int*)ws;     ws += align256((size_t)N * 4);
    int*    rowptr = (int*)ws;     ws += align256((size_t)(N + 1) * 4);
    int*    cursor = (int*)ws;     ws += align256((size_t)N * 4);
    int*    part   = (int*)ws;     ws += align256(256 * 4);
    int*    bcnt   = (int*)ws;     ws += align256((size_t)NB * 64 * 4);
    int*    bbase  = (int*)ws;     ws += align256((size_t)NB * 64 * 4);
    int*    tot    = (int*)ws;     ws += align256(64 * 4);
    int*    bstart = (int*)ws;     ws += align256(64 * 4);
    int*    perm   = (int*)ws;     ws += align256((size_t)N * 4);
    float*  dinv   = (float*)ws;   ws += align256((size_t)N * 4);
    int*    csrc   = (int*)ws;     ws += align256((size_t)E * 4);
    __half* bufA   = (__half*)ws;  ws += align256((size_t)N * HID_C * 2);
    __half* bufB   = (__half*)ws;  ws += align256((size_t)N * HID_C * 2);
    __half* bufC   = (__half*)ws;  ws += align256((size_t)N * HID_C * 2);

    const int T = 256;
    const int MT = N / 16;             // 3125 MFMA tiles
    const int LB = cdiv(MT, 4);        // mfma_lin blocks (4 waves each)
    const int P64B = cdiv(N, T / 16);  // prop64 blocks (16 QWs each)
    const int P40B = cdiv(N, T / 32);  // prop40 blocks (8 HWs each)

    // ---- CSR build + degree sort ----
    zero_detect_k<<<cdiv(N, T), T, 0, stream>>>(deg, N, (const unsigned int*)ei, flag);
    deg_hist_k<<<cdiv(E, T), T, 0, stream>>>(ei, flag, deg, E);
    scan_p1_k<<<NB, 256, 0, stream>>>(deg, part, N);
    scan_p2_k<<<1, 256, 0, stream>>>(part, NB, rowptr, N);
    scan_p3_k<<<NB, 256, 0, stream>>>(deg, part, rowptr, cursor, dinv, N);
    bhist_k<<<NB, 256, 0, stream>>>(deg, bcnt, N);
    bscanA_k<<<64, 256, 0, stream>>>(bcnt, bbase, tot, NB);
    bscanB_k<<<1, 64, 0, stream>>>(tot, bstart);
    perm_k<<<NB, 256, 0, stream>>>(deg, bbase, bstart, perm, N);
    csr_fill_k<<<cdiv(E, FILL_CHUNK) * 8, T, 0, stream>>>(ei, flag, cursor, csrc, E, N);

    // ---- conv0 (SGConv, K=2): linear folded first; output G-space ----
    mfma_lin_k<HID_C, IN_C, true, true><<<LB, 256, 0, stream>>>(x, W0, dinv, bufA, MT);
    prop64_k<false, false, false><<<P64B, T, 0, stream>>>(
        perm, rowptr, csrc, dinv, bufA, nullptr, nullptr, bufB, N);
    prop64_k<false, false, true><<<P64B, T, 0, stream>>>(
        perm, rowptr, csrc, dinv, bufB, nullptr, b0, bufC, N);  // + dinv*b0 -> Gh0

    // ---- conv1..conv3: leaky(APPNP(h)) entirely in G-space, Gh0 = bufC ----
    for (int r = 0; r < 3; ++r) {
        prop64_k<true, false, false><<<P64B, T, 0, stream>>>(
            perm, rowptr, csrc, dinv, bufC, bufC, nullptr, bufB, N);
        // in-place bufC write safe: Gh0[node] read only by the QW writing it
        prop64_k<true, true, false><<<P64B, T, 0, stream>>>(
            perm, rowptr, csrc, dinv, bufB, bufC, nullptr, bufC, N);
    }

    // ---- conv4 (SGConv, K=2): G-space lin (no scale), then 2 hops at 40ch ----
    mfma_lin_k<OUT_C, HID_C, false, false><<<LB, 256, 0, stream>>>(bufC, W4, dinv, bufA, MT);
    prop40_k<<<P40B, T, 0, stream>>>(perm, rowptr, csrc, dinv, bufA, bufB, N);
    prop40_softmax_k<<<P40B, T, 0, stream>>>(perm, rowptr, csrc, dinv, bufB, b4, out, N);
}

// Round 13
// 350.899 us; speedup vs baseline: 1.1205x; 1.0050x over previous
//
#include <hip/hip_runtime.h>
#include <hip/hip_fp16.h>
#include <math.h>

#define N_NODES 50000
#define N_EDGES 800000
#define IN_C 96
#define HID_C 64
#define OUT_C 40
#define ALPHA 0.2f
#define NEG_SLOPE 0.01f
#define QCAP 131072  // per-partition queue capacity; mean 100k, ~100 sigma margin

typedef _Float16 f16x8 __attribute__((ext_vector_type(8)));
typedef float f32x4 __attribute__((ext_vector_type(4)));

__device__ __forceinline__ int edge_at(const void* ei, int is64, long long pos) {
    return is64 ? (int)((const long long*)ei)[pos] : ((const int*)ei)[pos];
}

// ---------------- zero deg + qtail + edge dtype detect (fused) ----------------
__global__ void zero_detect_k(int* deg, int n, int* qtail, const unsigned int* ei, int* flag) {
    int i = blockIdx.x * blockDim.x + threadIdx.x;
    if (i < n) deg[i] = 0;
    if (i < 8) qtail[i] = 0;
    if (i == 0) {
        int is64 = 1;
        for (int j = 1; j < 16; j += 2)
            if (ei[j] != 0u) is64 = 0;
        *flag = is64;
    }
}

// ---- phase A: one pass over edges. Per 1024-edge tile: LDS rank counters ->
// ONE block-level atomic per partition (reserves a contiguous queue slice) ->
// threads write (s,d) at base+rank (block-private windows, full-line writes).
// Also fuses the degree histogram (reads dst anyway).
// R9 lesson: never per-wave-iteration atomics on few counters; block-level
// reservation is 8 atomics / 1024 edges (~6k total on 8 addresses).
__global__ void bucketA_k(const void* ei, const int* flag, int* __restrict__ deg,
                          int* __restrict__ qtail, int2* __restrict__ queue, int E) {
    __shared__ int cnt[8], qb[8];
    int f = *flag;
    int e0 = blockIdx.x * 1024;
    if (threadIdx.x < 8) cnt[threadIdx.x] = 0;
    __syncthreads();
    int s[4], d[4], p[4], r[4];
    #pragma unroll
    for (int k = 0; k < 4; ++k) {
        int e = e0 + threadIdx.x + k * 256;
        if (e < E) {
            d[k] = edge_at(ei, f, (long long)E + e);
            s[k] = edge_at(ei, f, e);
            atomicAdd(&deg[d[k]], 1);
            p[k] = d[k] / (N_NODES / 8);
            if (p[k] > 7) p[k] = 7;
            r[k] = atomicAdd(&cnt[p[k]], 1);
        } else p[k] = -1;
    }
    __syncthreads();
    if (threadIdx.x < 8) qb[threadIdx.x] = atomicAdd(&qtail[threadIdx.x], cnt[threadIdx.x]);
    __syncthreads();
    #pragma unroll
    for (int k = 0; k < 4; ++k) {
        if (p[k] >= 0) {
            int pos = qb[p[k]] + r[k];
            if (pos < QCAP) queue[(size_t)p[k] * QCAP + pos] = make_int2(s[k], d[k]);
        }
    }
}

// ---- phase B: per-partition streaming read of queue, scatter into the
// L2-resident csrc window (blockIdx%8 = partition ~ XCD).
__global__ void bucketB_k(const int* __restrict__ qtail, const int2* __restrict__ queue,
                          int* __restrict__ cursor, int* __restrict__ csrc) {
    int p = blockIdx.x & 7;
    int j = blockIdx.x >> 3;
    int J = gridDim.x >> 3;
    int n = qtail[p]; if (n > QCAP) n = QCAP;
    const int2* q = queue + (size_t)p * QCAP;
    for (int i = j * blockDim.x + threadIdx.x; i < n; i += J * blockDim.x) {
        int2 e = q[i];
        int pos = atomicAdd(&cursor[e.y], 1);
        csrc[pos] = e.x;
    }
}

// ---- parallel 3-phase exclusive scan over deg[n] ----
__global__ void scan_p1_k(const int* __restrict__ deg, int* __restrict__ part, int n) {
    __shared__ int sm[256];
    int t = threadIdx.x, i = blockIdx.x * 256 + t;
    int v = (i < n) ? deg[i] : 0;
    sm[t] = v;
    __syncthreads();
    for (int off = 1; off < 256; off <<= 1) {
        int u = (t >= off) ? sm[t - off] : 0;
        __syncthreads();
        sm[t] += u;
        __syncthreads();
    }
    if (t == 255) part[blockIdx.x] = sm[255];
}

__global__ void scan_p2_k(int* part, int nb, int* rowptr, int n) {
    __shared__ int sm[256];
    int t = threadIdx.x;
    int v = (t < nb) ? part[t] : 0;
    sm[t] = v;
    __syncthreads();
    for (int off = 1; off < 256; off <<= 1) {
        int u = (t >= off) ? sm[t - off] : 0;
        __syncthreads();
        sm[t] += u;
        __syncthreads();
    }
    if (t < nb) part[t] = sm[t] - v;  // exclusive
    if (t == 255) rowptr[n] = sm[255];
}

// scan_p3 + bucket histogram fused (both consume deg with the same grid)
__global__ void scan_p3_k(const int* __restrict__ deg, const int* __restrict__ part,
                          int* __restrict__ rowptr, int* __restrict__ cursor,
                          float* __restrict__ dinv, int* __restrict__ bcnt, int n) {
    __shared__ int sm[256];
    __shared__ int h[64];
    int t = threadIdx.x, i = blockIdx.x * 256 + t;
    if (t < 64) h[t] = 0;
    int v = (i < n) ? deg[i] : 0;
    sm[t] = v;
    __syncthreads();
    for (int off = 1; off < 256; off <<= 1) {
        int u = (t >= off) ? sm[t - off] : 0;
        __syncthreads();
        sm[t] += u;
        __syncthreads();
    }
    if (i < n) {
        int excl = sm[t] - v + part[blockIdx.x];
        rowptr[i] = excl;
        cursor[i] = excl;
        dinv[i] = rsqrtf((float)v + 1.0f);  // +1 self loop
        int dd = v; if (dd > 63) dd = 63;
        atomicAdd(&h[63 - dd], 1);          // bucket = 63-deg (descending)
    }
    __syncthreads();
    if (t < 64) bcnt[blockIdx.x * 64 + t] = h[t];
}

// bscanA: one block per bucket; parallel exclusive scan over nb block-counts.
__global__ void bscanA_k(const int* __restrict__ bcnt, int* __restrict__ bbase,
                         int* __restrict__ tot, int nb) {
    __shared__ int sm[256];
    int b = blockIdx.x;   // bucket
    int t = threadIdx.x;  // block index within bucket
    int v = (t < nb) ? bcnt[t * 64 + b] : 0;
    sm[t] = v;
    __syncthreads();
    for (int off = 1; off < 256; off <<= 1) {
        int u = (t >= off) ? sm[t - off] : 0;
        __syncthreads();
        sm[t] += u;
        __syncthreads();
    }
    if (t < nb) bbase[t * 64 + b] = sm[t] - v;  // exclusive, per-bucket local
    if (t == 255) tot[b] = sm[255];
}

// perm + bucket-start scan fused (each block redoes the trivial 64-scan)
__global__ void perm_k(const int* __restrict__ deg, const int* __restrict__ bbase,
                       const int* __restrict__ tot, int* __restrict__ perm, int n) {
    __shared__ int h[64], bs[64];
    int t = threadIdx.x, i = blockIdx.x * 256 + t;
    if (t < 64) { h[t] = 0; bs[t] = tot[t]; }
    __syncthreads();
    if (t == 0) {
        int run = 0;
        for (int k = 0; k < 64; ++k) { int v = bs[k]; bs[k] = run; run += v; }
    }
    __syncthreads();
    if (i < n) {
        int d = deg[i]; if (d > 63) d = 63;
        int b = 63 - d;
        int rank = atomicAdd(&h[b], 1);
        perm[bs[b] + bbase[blockIdx.x * 64 + b] + rank] = i;
    }
}

// ---------------- C=64 prop: quarter-wave per NODE (degree-sorted) -------------
template <bool COMBINE, bool LEAKY, bool BIAS>
__global__ void prop64_k(const int* __restrict__ perm,
                         const int* __restrict__ rowptr, const int* __restrict__ csrc,
                         const float* __restrict__ dinv,
                         const __half* __restrict__ in, const __half* __restrict__ h0,
                         const float* __restrict__ bias,
                         __half* __restrict__ out, int N) {
    int qw = blockIdx.x * (blockDim.x >> 4) + (threadIdx.x >> 4);
    int ci = threadIdx.x & 15;
    if (qw >= N) return;
    int node = perm[qw];
    const float2* in4 = (const float2*)in;  // 8 B = 4 halves (bit-carrier)
    f32x4 acc;
    {   // self-loop term G[node]
        float2 r = in4[node * 16 + ci];
        float2 a = __half22float2(*(const __half2*)&r.x);
        float2 b = __half22float2(*(const __half2*)&r.y);
        acc[0] = a.x; acc[1] = a.y; acc[2] = b.x; acc[3] = b.y;
    }
    int r0 = rowptr[node], r1 = rowptr[node + 1];
    int i = r0;
    for (; i + 3 < r1; i += 4) {  // 4 rows in flight per QW
        int s0 = csrc[i], s1 = csrc[i + 1], s2 = csrc[i + 2], s3 = csrc[i + 3];
        float2 v0 = in4[s0 * 16 + ci];
        float2 v1 = in4[s1 * 16 + ci];
        float2 v2 = in4[s2 * 16 + ci];
        float2 v3 = in4[s3 * 16 + ci];
        float2 a0 = __half22float2(*(const __half2*)&v0.x), b0 = __half22float2(*(const __half2*)&v0.y);
        float2 a1 = __half22float2(*(const __half2*)&v1.x), b1 = __half22float2(*(const __half2*)&v1.y);
        float2 a2 = __half22float2(*(const __half2*)&v2.x), b2 = __half22float2(*(const __half2*)&v2.y);
        float2 a3 = __half22float2(*(const __half2*)&v3.x), b3 = __half22float2(*(const __half2*)&v3.y);
        acc[0] += (a0.x + a1.x) + (a2.x + a3.x);
        acc[1] += (a0.y + a1.y) + (a2.y + a3.y);
        acc[2] += (b0.x + b1.x) + (b2.x + b3.x);
        acc[3] += (b0.y + b1.y) + (b2.y + b3.y);
    }
    for (; i < r1; ++i) {
        float2 v0 = in4[csrc[i] * 16 + ci];
        float2 a0 = __half22float2(*(const __half2*)&v0.x), b0 = __half22float2(*(const __half2*)&v0.y);
        acc[0] += a0.x; acc[1] += a0.y; acc[2] += b0.x; acc[3] += b0.y;
    }
    float di = dinv[node];
    float sc = di * di;
    float4 v;
    v.x = sc * acc[0]; v.y = sc * acc[1]; v.z = sc * acc[2]; v.w = sc * acc[3];
    if (BIAS) {
        const float4 b = ((const float4*)bias)[ci];
        v.x += di * b.x; v.y += di * b.y; v.z += di * b.z; v.w += di * b.w;
    }
    if (COMBINE) {
        float2 r = ((const float2*)h0)[node * 16 + ci];
        float2 a = __half22float2(*(const __half2*)&r.x);
        float2 b = __half22float2(*(const __half2*)&r.y);
        v.x = (1.0f - ALPHA) * v.x + ALPHA * a.x;
        v.y = (1.0f - ALPHA) * v.y + ALPHA * a.y;
        v.z = (1.0f - ALPHA) * v.z + ALPHA * b.x;
        v.w = (1.0f - ALPHA) * v.w + ALPHA * b.y;
    }
    if (LEAKY) {
        v.x = v.x > 0.0f ? v.x : NEG_SLOPE * v.x;
        v.y = v.y > 0.0f ? v.y : NEG_SLOPE * v.y;
        v.z = v.z > 0.0f ? v.z : NEG_SLOPE * v.z;
        v.w = v.w > 0.0f ? v.w : NEG_SLOPE * v.w;
    }
    float2 o;
    *(__half2*)&o.x = __float22half2_rn(make_float2(v.x, v.y));
    *(__half2*)&o.y = __float22half2_rn(make_float2(v.z, v.w));
    ((float2*)out)[node * 16 + ci] = o;
}

// ---------------- C=40 prop: half-wave per NODE (degree-sorted) ----------------
__global__ void prop40_k(const int* __restrict__ perm,
                         const int* __restrict__ rowptr, const int* __restrict__ csrc,
                         const float* __restrict__ dinv,
                         const __half* __restrict__ in, __half* __restrict__ out, int N) {
    constexpr int CP = OUT_C / 2;  // 20
    int hw = blockIdx.x * (blockDim.x >> 5) + (threadIdx.x >> 5);
    int ci = threadIdx.x & 31;
    if (hw >= N) return;
    int node = perm[hw];
    bool act = ci < CP;
    const __half2* in2 = (const __half2*)in;
    float2 acc = make_float2(0.0f, 0.0f);
    if (act) {
        acc = __half22float2(in2[(long long)node * CP + ci]);
    }
    int r0 = rowptr[node], r1 = rowptr[node + 1];
    int i = r0;
    for (; i + 3 < r1; i += 4) {
        int s0 = csrc[i], s1 = csrc[i + 1], s2 = csrc[i + 2], s3 = csrc[i + 3];
        if (act) {
            float2 v0 = __half22float2(in2[(long long)s0 * CP + ci]);
            float2 v1 = __half22float2(in2[(long long)s1 * CP + ci]);
            float2 v2 = __half22float2(in2[(long long)s2 * CP + ci]);
            float2 v3 = __half22float2(in2[(long long)s3 * CP + ci]);
            acc.x += (v0.x + v1.x) + (v2.x + v3.x);
            acc.y += (v0.y + v1.y) + (v2.y + v3.y);
        }
    }
    for (; i < r1; ++i) {
        int s0 = csrc[i];
        if (act) {
            float2 v0 = __half22float2(in2[(long long)s0 * CP + ci]);
            acc.x += v0.x; acc.y += v0.y;
        }
    }
    if (act) {
        float di = dinv[node];
        float sc = di * di;
        ((__half2*)out)[(long long)node * CP + ci] =
            __float22half2_rn(make_float2(sc * acc.x, sc * acc.y));
    }
}

// ---------------- final C=40 prop + b4 + log_softmax fused, fp32 out -----------
__global__ void prop40_softmax_k(const int* __restrict__ perm,
                                 const int* __restrict__ rowptr, const int* __restrict__ csrc,
                                 const float* __restrict__ dinv,
                                 const __half* __restrict__ in, const float* __restrict__ bias,
                                 float* __restrict__ out, int N) {
    constexpr int CP = OUT_C / 2;  // 20
    int hw = blockIdx.x * (blockDim.x >> 5) + (threadIdx.x >> 5);
    int ci = threadIdx.x & 31;
    if (hw >= N) return;
    int node = perm[hw];
    bool act = ci < CP;
    const __half2* in2 = (const __half2*)in;
    float2 acc = make_float2(0.0f, 0.0f);
    if (act) {
        acc = __half22float2(in2[(long long)node * CP + ci]);
    }
    int r0 = rowptr[node], r1 = rowptr[node + 1];
    int i = r0;
    for (; i + 3 < r1; i += 4) {
        int s0 = csrc[i], s1 = csrc[i + 1], s2 = csrc[i + 2], s3 = csrc[i + 3];
        if (act) {
            float2 v0 = __half22float2(in2[(long long)s0 * CP + ci]);
            float2 v1 = __half22float2(in2[(long long)s1 * CP + ci]);
            float2 v2 = __half22float2(in2[(long long)s2 * CP + ci]);
            float2 v3 = __half22float2(in2[(long long)s3 * CP + ci]);
            acc.x += (v0.x + v1.x) + (v2.x + v3.x);
            acc.y += (v0.y + v1.y) + (v2.y + v3.y);
        }
    }
    for (; i < r1; ++i) {
        int s0 = csrc[i];
        if (act) {
            float2 v0 = __half22float2(in2[(long long)s0 * CP + ci]);
            acc.x += v0.x; acc.y += v0.y;
        }
    }
    float di = dinv[node];
    float2 v = make_float2(-INFINITY, -INFINITY);
    if (act) {
        v.x = di * acc.x + bias[2 * ci];
        v.y = di * acc.y + bias[2 * ci + 1];
    }
    float m = fmaxf(v.x, v.y);
    #pragma unroll
    for (int off = 16; off >= 1; off >>= 1) m = fmaxf(m, __shfl_xor(m, off));
    float e = act ? (expf(v.x - m) + expf(v.y - m)) : 0.0f;
    #pragma unroll
    for (int off = 16; off >= 1; off >>= 1) e += __shfl_xor(e, off);
    float ls = m + logf(e);
    if (act)
        ((float2*)out)[(long long)node * CP + ci] = make_float2(v.x - ls, v.y - ls);
}

// ---------------- MFMA dense linear: out[m,o] = sum_k in[m,k]*W[o,k] -----------
template <int O, int K, bool FP32IN, bool SCALE>
__global__ void __launch_bounds__(256) mfma_lin_k(const void* __restrict__ in_,
                                                  const float* __restrict__ W,
                                                  const float* __restrict__ dinv,
                                                  __half* __restrict__ out, int Mtiles) {
    constexpr int P2 = 52;  // half2 pitch (104 halves = 208 B rows, 16B-aligned)
    __shared__ __half2 wsh[O * P2];
    for (int idx = threadIdx.x; idx < O * (K / 2); idx += 256) {
        int o = idx / (K / 2), kk = idx - o * (K / 2);
        float2 w2 = ((const float2*)W)[o * (K / 2) + kk];
        wsh[o * P2 + kk] = __floats2half2_rn(w2.x, w2.y);
    }
    __syncthreads();
    int wave = (blockIdx.x * 256 + threadIdx.x) >> 6;
    if (wave >= Mtiles) return;
    int lane = threadIdx.x & 63;
    int lm = lane & 15, q = lane >> 4;
    long long m0 = (long long)wave * 16;
    constexpr int NT = (O + 15) / 16;
    f32x4 acc[NT];
    #pragma unroll
    for (int j = 0; j < NT; ++j) acc[j] = (f32x4){0.f, 0.f, 0.f, 0.f};
    const __half* wsp = (const __half*)wsh;
    #pragma unroll
    for (int k0 = 0; k0 < K; k0 += 32) {
        f16x8 a;
        if (FP32IN) {
            const float* xr = (const float*)in_ + (m0 + lm) * K + k0 + q * 8;
            float4 x0 = ((const float4*)xr)[0];
            float4 x1 = ((const float4*)xr)[1];
            a = (f16x8){(_Float16)x0.x, (_Float16)x0.y, (_Float16)x0.z, (_Float16)x0.w,
                        (_Float16)x1.x, (_Float16)x1.y, (_Float16)x1.z, (_Float16)x1.w};
        } else {
            const __half* xr = (const __half*)in_ + (m0 + lm) * K + k0 + q * 8;
            a = *(const f16x8*)xr;
        }
        #pragma unroll
        for (int j = 0; j < NT; ++j) {
            f16x8 b = *(const f16x8*)(wsp + (16 * j + lm) * (2 * P2) + k0 + q * 8);
            acc[j] = __builtin_amdgcn_mfma_f32_16x16x32_f16(a, b, acc[j], 0, 0, 0);
        }
    }
    #pragma unroll
    for (int r = 0; r < 4; ++r) {
        long long m = m0 + q * 4 + r;
        float sc = SCALE ? dinv[m] : 1.0f;
        #pragma unroll
        for (int j = 0; j < NT; ++j) {
            int col = 16 * j + lm;
            if (col < O) out[m * O + col] = __float2half(acc[j][r] * sc);
        }
    }
}

// ---------------- launcher ----------------
static inline int cdiv(long long a, long long b) { return (int)((a + b - 1) / b); }
static inline size_t align256(size_t x) { return (x + 255) & ~(size_t)255; }

extern "C" void kernel_launch(void* const* d_in, const int* in_sizes, int n_in,
                              void* d_out, int out_size, void* d_ws, size_t ws_size,
                              hipStream_t stream) {
    const float* x  = (const float*)d_in[0];
    const void*  ei = d_in[1];
    const float* W0 = (const float*)d_in[2];
    const float* b0 = (const float*)d_in[3];
    const float* W4 = (const float*)d_in[4];
    const float* b4 = (const float*)d_in[5];
    float* out = (float*)d_out;

    const int N = N_NODES, E = N_EDGES;
    const int NB = cdiv(N, 256);  // 196
    char* ws = (char*)d_ws;
    int*    flag   = (int*)ws;     ws += 256;
    int*    deg    = (int*)ws;     ws += align256((size_t)N * 4);
    int*    rowptr = (int*)ws;     ws += align256((size_t)(N + 1) * 4);
    int*    cursor = (int*)ws;     ws += align256((size_t)N * 4);
    int*    part   = (int*)ws;     ws += align256(256 * 4);
    int*    bcnt   = (int*)ws;     ws += align256((size_t)NB * 64 * 4);
    int*    bbase  = (int*)ws;     ws += align256((size_t)NB * 64 * 4);
    int*    tot    = (int*)ws;     ws += align256(64 * 4);
    int*    qtail  = (int*)ws;     ws += align256(8 * 4);
    int*    perm   = (int*)ws;     ws += align256((size_t)N * 4);
    float*  dinv   = (float*)ws;   ws += align256((size_t)N * 4);
    int*    csrc   = (int*)ws;     ws += align256((size_t)E * 4);
    int2*   queue  = (int2*)ws;    ws += align256((size_t)8 * QCAP * 8);
    __half* bufA   = (__half*)ws;  ws += align256((size_t)N * HID_C * 2);
    __half* bufB   = (__half*)ws;  ws += align256((size_t)N * HID_C * 2);
    __half* bufC   = (__half*)ws;  ws += align256((size_t)N * HID_C * 2);

    const int T = 256;
    const int MT = N / 16;             // 3125 MFMA tiles
    const int LB = cdiv(MT, 4);        // mfma_lin blocks (4 waves each)
    const int P64B = cdiv(N, T / 16);  // prop64 blocks (16 QWs each)
    const int P40B = cdiv(N, T / 32);  // prop40 blocks (8 HWs each)

    // ---- CSR build (two-phase partition queues) + degree sort ----
    zero_detect_k<<<cdiv(N, T), T, 0, stream>>>(deg, N, qtail, (const unsigned int*)ei, flag);
    bucketA_k<<<cdiv(E, 1024), T, 0, stream>>>(ei, flag, deg, qtail, queue, E);
    scan_p1_k<<<NB, 256, 0, stream>>>(deg, part, N);
    scan_p2_k<<<1, 256, 0, stream>>>(part, NB, rowptr, N);
    scan_p3_k<<<NB, 256, 0, stream>>>(deg, part, rowptr, cursor, dinv, bcnt, N);
    bscanA_k<<<64, 256, 0, stream>>>(bcnt, bbase, tot, NB);
    perm_k<<<NB, 256, 0, stream>>>(deg, bbase, tot, perm, N);
    bucketB_k<<<8 * 64, T, 0, stream>>>(qtail, queue, cursor, csrc);

    // ---- conv0 (SGConv, K=2): linear folded first; output G-space ----
    mfma_lin_k<HID_C, IN_C, true, true><<<LB, 256, 0, stream>>>(x, W0, dinv, bufA, MT);
    prop64_k<false, false, false><<<P64B, T, 0, stream>>>(
        perm, rowptr, csrc, dinv, bufA, nullptr, nullptr, bufB, N);
    prop64_k<false, false, true><<<P64B, T, 0, stream>>>(
        perm, rowptr, csrc, dinv, bufB, nullptr, b0, bufC, N);  // + dinv*b0 -> Gh0

    // ---- conv1..conv3: leaky(APPNP(h)) entirely in G-space, Gh0 = bufC ----
    for (int r = 0; r < 3; ++r) {
        prop64_k<true, false, false><<<P64B, T, 0, stream>>>(
            perm, rowptr, csrc, dinv, bufC, bufC, nullptr, bufB, N);
        // in-place bufC write safe: Gh0[node] read only by the QW writing it
        prop64_k<true, true, false><<<P64B, T, 0, stream>>>(
            perm, rowptr, csrc, dinv, bufB, bufC, nullptr, bufC, N);
    }

    // ---- conv4 (SGConv, K=2): G-space lin (no scale), then 2 hops at 40ch ----
    mfma_lin_k<OUT_C, HID_C, false, false><<<LB, 256, 0, stream>>>(bufC, W4, dinv, bufA, MT);
    prop40_k<<<P40B, T, 0, stream>>>(perm, rowptr, csrc, dinv, bufA, bufB, N);
    prop40_softmax_k<<<P40B, T, 0, stream>>>(perm, rowptr, csrc, dinv, bufB, b4, out, N);
}

// Round 14
// 345.428 us; speedup vs baseline: 1.1382x; 1.0158x over previous
//
#include <hip/hip_runtime.h>
#include <hip/hip_fp16.h>
#include <math.h>

#define N_NODES 50000
#define N_EDGES 800000
#define IN_C 96
#define HID_C 64
#define OUT_C 40
#define ALPHA 0.2f
#define NEG_SLOPE 0.01f
#define QCAP 131072  // per-partition queue capacity; mean 100k, ~100 sigma margin

typedef _Float16 f16x8 __attribute__((ext_vector_type(8)));
typedef float f32x4 __attribute__((ext_vector_type(4)));

__device__ __forceinline__ int edge_at(const void* ei, int is64, long long pos) {
    return is64 ? (int)((const long long*)ei)[pos] : ((const int*)ei)[pos];
}

// ---------------- zero deg + qtail + edge dtype detect (fused) ----------------
__global__ void zero_detect_k(int* deg, int n, int* qtail, const unsigned int* ei, int* flag) {
    int i = blockIdx.x * blockDim.x + threadIdx.x;
    if (i < n) deg[i] = 0;
    if (i < 8) qtail[i] = 0;
    if (i == 0) {
        int is64 = 1;
        for (int j = 1; j < 16; j += 2)
            if (ei[j] != 0u) is64 = 0;
        *flag = is64;
    }
}

// ---- phase A: one pass over edges. Per 1024-edge tile: LDS rank counters ->
// ONE block-level atomic per partition -> threads write (s,d) at base+rank.
// Fuses the degree histogram. (R9 lesson: block-level reservation, not
// per-wave ballot atomics on few counters.)
__global__ void bucketA_k(const void* ei, const int* flag, int* __restrict__ deg,
                          int* __restrict__ qtail, int2* __restrict__ queue, int E) {
    __shared__ int cnt[8], qb[8];
    int f = *flag;
    int e0 = blockIdx.x * 1024;
    if (threadIdx.x < 8) cnt[threadIdx.x] = 0;
    __syncthreads();
    int s[4], d[4], p[4], r[4];
    #pragma unroll
    for (int k = 0; k < 4; ++k) {
        int e = e0 + threadIdx.x + k * 256;
        if (e < E) {
            d[k] = edge_at(ei, f, (long long)E + e);
            s[k] = edge_at(ei, f, e);
            atomicAdd(&deg[d[k]], 1);
            p[k] = d[k] / (N_NODES / 8);
            if (p[k] > 7) p[k] = 7;
            r[k] = atomicAdd(&cnt[p[k]], 1);
        } else p[k] = -1;
    }
    __syncthreads();
    if (threadIdx.x < 8) qb[threadIdx.x] = atomicAdd(&qtail[threadIdx.x], cnt[threadIdx.x]);
    __syncthreads();
    #pragma unroll
    for (int k = 0; k < 4; ++k) {
        if (p[k] >= 0) {
            int pos = qb[p[k]] + r[k];
            if (pos < QCAP) queue[(size_t)p[k] * QCAP + pos] = make_int2(s[k], d[k]);
        }
    }
}

// ---- phase B: per-partition streaming read of queue, scatter into the
// L2-resident csrc window (blockIdx%8 = partition ~ XCD).
__global__ void bucketB_k(const int* __restrict__ qtail, const int2* __restrict__ queue,
                          int* __restrict__ cursor, int* __restrict__ csrc) {
    int p = blockIdx.x & 7;
    int j = blockIdx.x >> 3;
    int J = gridDim.x >> 3;
    int n = qtail[p]; if (n > QCAP) n = QCAP;
    const int2* q = queue + (size_t)p * QCAP;
    for (int i = j * blockDim.x + threadIdx.x; i < n; i += J * blockDim.x) {
        int2 e = q[i];
        int pos = atomicAdd(&cursor[e.y], 1);
        csrc[pos] = e.x;
    }
}

// ---- parallel 3-phase exclusive scan over deg[n] ----
__global__ void scan_p1_k(const int* __restrict__ deg, int* __restrict__ part, int n) {
    __shared__ int sm[256];
    int t = threadIdx.x, i = blockIdx.x * 256 + t;
    int v = (i < n) ? deg[i] : 0;
    sm[t] = v;
    __syncthreads();
    for (int off = 1; off < 256; off <<= 1) {
        int u = (t >= off) ? sm[t - off] : 0;
        __syncthreads();
        sm[t] += u;
        __syncthreads();
    }
    if (t == 255) part[blockIdx.x] = sm[255];
}

__global__ void scan_p2_k(int* part, int nb, int* rowptr, int n) {
    __shared__ int sm[256];
    int t = threadIdx.x;
    int v = (t < nb) ? part[t] : 0;
    sm[t] = v;
    __syncthreads();
    for (int off = 1; off < 256; off <<= 1) {
        int u = (t >= off) ? sm[t - off] : 0;
        __syncthreads();
        sm[t] += u;
        __syncthreads();
    }
    if (t < nb) part[t] = sm[t] - v;  // exclusive
    if (t == 255) rowptr[n] = sm[255];
}

// scan_p3 + bucket histogram fused (both consume deg with the same grid)
__global__ void scan_p3_k(const int* __restrict__ deg, const int* __restrict__ part,
                          int* __restrict__ rowptr, int* __restrict__ cursor,
                          float* __restrict__ dinv, int* __restrict__ bcnt, int n) {
    __shared__ int sm[256];
    __shared__ int h[64];
    int t = threadIdx.x, i = blockIdx.x * 256 + t;
    if (t < 64) h[t] = 0;
    int v = (i < n) ? deg[i] : 0;
    sm[t] = v;
    __syncthreads();
    for (int off = 1; off < 256; off <<= 1) {
        int u = (t >= off) ? sm[t - off] : 0;
        __syncthreads();
        sm[t] += u;
        __syncthreads();
    }
    if (i < n) {
        int excl = sm[t] - v + part[blockIdx.x];
        rowptr[i] = excl;
        cursor[i] = excl;
        dinv[i] = rsqrtf((float)v + 1.0f);  // +1 self loop
        int dd = v; if (dd > 63) dd = 63;
        atomicAdd(&h[63 - dd], 1);          // bucket = 63-deg (descending)
    }
    __syncthreads();
    if (t < 64) bcnt[blockIdx.x * 64 + t] = h[t];
}

// bscanA: one block per bucket; parallel exclusive scan over nb block-counts.
__global__ void bscanA_k(const int* __restrict__ bcnt, int* __restrict__ bbase,
                         int* __restrict__ tot, int nb) {
    __shared__ int sm[256];
    int b = blockIdx.x;   // bucket
    int t = threadIdx.x;  // block index within bucket
    int v = (t < nb) ? bcnt[t * 64 + b] : 0;
    sm[t] = v;
    __syncthreads();
    for (int off = 1; off < 256; off <<= 1) {
        int u = (t >= off) ? sm[t - off] : 0;
        __syncthreads();
        sm[t] += u;
        __syncthreads();
    }
    if (t < nb) bbase[t * 64 + b] = sm[t] - v;  // exclusive, per-bucket local
    if (t == 255) tot[b] = sm[255];
}

// perm + bucket-start scan fused (each block redoes the trivial 64-scan)
__global__ void perm_k(const int* __restrict__ deg, const int* __restrict__ bbase,
                       const int* __restrict__ tot, int* __restrict__ perm, int n) {
    __shared__ int h[64], bs[64];
    int t = threadIdx.x, i = blockIdx.x * 256 + t;
    if (t < 64) { h[t] = 0; bs[t] = tot[t]; }
    __syncthreads();
    if (t == 0) {
        int run = 0;
        for (int k = 0; k < 64; ++k) { int v = bs[k]; bs[k] = run; run += v; }
    }
    __syncthreads();
    if (i < n) {
        int d = deg[i]; if (d > 63) d = 63;
        int b = 63 - d;
        int rank = atomicAdd(&h[b], 1);
        perm[bs[b] + bbase[blockIdx.x * 64 + b] + rank] = i;
    }
}

// ---------------- C=64 prop: 8-lane group per NODE (degree-sorted) -------------
// Lane ci owns channels [8ci,8ci+8) (16 B of the 128 B row) end-to-end; one
// wave VMEM instruction gathers 8 rows (8 groups x float4). 4-deep unroll ->
// 32 rows in flight per wave. G-space math (G = dinv*h).
__device__ __forceinline__ void add8(float* acc, float4 v, float w) {
    const __half2* hp = (const __half2*)&v;
    #pragma unroll
    for (int j = 0; j < 4; ++j) {
        float2 f = __half22float2(hp[j]);
        acc[2 * j] += w * f.x;
        acc[2 * j + 1] += w * f.y;
    }
}

template <bool COMBINE, bool LEAKY, bool BIAS>
__global__ void __launch_bounds__(256) prop64_k(
        const int* __restrict__ perm,
        const int* __restrict__ rowptr, const int* __restrict__ csrc,
        const float* __restrict__ dinv,
        const __half* __restrict__ in, const __half* __restrict__ h0,
        const float* __restrict__ bias,
        __half* __restrict__ out, int N) {
    int g = blockIdx.x * (blockDim.x >> 3) + (threadIdx.x >> 3);
    int ci = threadIdx.x & 7;  // 8 lanes x 8ch = 64 channels
    if (g >= N) return;
    int node = perm[g];
    const float4* in8 = (const float4*)in;  // 16 B = 8 halves (bit-carrier)
    float acc[8];
    {   // self-loop term G[node]
        float4 r = in8[node * 8 + ci];
        const __half2* hp = (const __half2*)&r;
        #pragma unroll
        for (int j = 0; j < 4; ++j) {
            float2 f = __half22float2(hp[j]);
            acc[2 * j] = f.x;
            acc[2 * j + 1] = f.y;
        }
    }
    int r0 = rowptr[node], r1 = rowptr[node + 1];
    int i = r0;
    for (; i + 3 < r1; i += 4) {  // 4 rows in flight per group
        int s0 = csrc[i], s1 = csrc[i + 1], s2 = csrc[i + 2], s3 = csrc[i + 3];
        float4 v0 = in8[s0 * 8 + ci];
        float4 v1 = in8[s1 * 8 + ci];
        float4 v2 = in8[s2 * 8 + ci];
        float4 v3 = in8[s3 * 8 + ci];
        add8(acc, v0, 1.0f);
        add8(acc, v1, 1.0f);
        add8(acc, v2, 1.0f);
        add8(acc, v3, 1.0f);
    }
    for (; i < r1; ++i) {
        float4 v0 = in8[csrc[i] * 8 + ci];
        add8(acc, v0, 1.0f);
    }
    float di = dinv[node];
    float sc = di * di;
    float v[8];
    #pragma unroll
    for (int j = 0; j < 8; ++j) v[j] = sc * acc[j];
    if (BIAS) {
        float4 b0v = ((const float4*)bias)[2 * ci];
        float4 b1v = ((const float4*)bias)[2 * ci + 1];
        v[0] += di * b0v.x; v[1] += di * b0v.y; v[2] += di * b0v.z; v[3] += di * b0v.w;
        v[4] += di * b1v.x; v[5] += di * b1v.y; v[6] += di * b1v.z; v[7] += di * b1v.w;
    }
    if (COMBINE) {
        float4 r = ((const float4*)h0)[node * 8 + ci];
        const __half2* hp = (const __half2*)&r;
        #pragma unroll
        for (int j = 0; j < 4; ++j) {
            float2 f = __half22float2(hp[j]);
            v[2 * j]     = (1.0f - ALPHA) * v[2 * j]     + ALPHA * f.x;
            v[2 * j + 1] = (1.0f - ALPHA) * v[2 * j + 1] + ALPHA * f.y;
        }
    }
    if (LEAKY) {
        #pragma unroll
        for (int j = 0; j < 8; ++j) v[j] = v[j] > 0.0f ? v[j] : NEG_SLOPE * v[j];
    }
    float4 o;
    __half2* op = (__half2*)&o;
    #pragma unroll
    for (int j = 0; j < 4; ++j)
        op[j] = __float22half2_rn(make_float2(v[2 * j], v[2 * j + 1]));
    ((float4*)out)[node * 8 + ci] = o;
}

// ---------------- C=40 prop: half-wave per NODE (degree-sorted) ----------------
__global__ void prop40_k(const int* __restrict__ perm,
                         const int* __restrict__ rowptr, const int* __restrict__ csrc,
                         const float* __restrict__ dinv,
                         const __half* __restrict__ in, __half* __restrict__ out, int N) {
    constexpr int CP = OUT_C / 2;  // 20
    int hw = blockIdx.x * (blockDim.x >> 5) + (threadIdx.x >> 5);
    int ci = threadIdx.x & 31;
    if (hw >= N) return;
    int node = perm[hw];
    bool act = ci < CP;
    const __half2* in2 = (const __half2*)in;
    float2 acc = make_float2(0.0f, 0.0f);
    if (act) {
        acc = __half22float2(in2[(long long)node * CP + ci]);
    }
    int r0 = rowptr[node], r1 = rowptr[node + 1];
    int i = r0;
    for (; i + 3 < r1; i += 4) {
        int s0 = csrc[i], s1 = csrc[i + 1], s2 = csrc[i + 2], s3 = csrc[i + 3];
        if (act) {
            float2 v0 = __half22float2(in2[(long long)s0 * CP + ci]);
            float2 v1 = __half22float2(in2[(long long)s1 * CP + ci]);
            float2 v2 = __half22float2(in2[(long long)s2 * CP + ci]);
            float2 v3 = __half22float2(in2[(long long)s3 * CP + ci]);
            acc.x += (v0.x + v1.x) + (v2.x + v3.x);
            acc.y += (v0.y + v1.y) + (v2.y + v3.y);
        }
    }
    for (; i < r1; ++i) {
        int s0 = csrc[i];
        if (act) {
            float2 v0 = __half22float2(in2[(long long)s0 * CP + ci]);
            acc.x += v0.x; acc.y += v0.y;
        }
    }
    if (act) {
        float di = dinv[node];
        float sc = di * di;
        ((__half2*)out)[(long long)node * CP + ci] =
            __float22half2_rn(make_float2(sc * acc.x, sc * acc.y));
    }
}

// ---------------- final C=40 prop + b4 + log_softmax fused, fp32 out -----------
__global__ void prop40_softmax_k(const int* __restrict__ perm,
                                 const int* __restrict__ rowptr, const int* __restrict__ csrc,
                                 const float* __restrict__ dinv,
                                 const __half* __restrict__ in, const float* __restrict__ bias,
                                 float* __restrict__ out, int N) {
    constexpr int CP = OUT_C / 2;  // 20
    int hw = blockIdx.x * (blockDim.x >> 5) + (threadIdx.x >> 5);
    int ci = threadIdx.x & 31;
    if (hw >= N) return;
    int node = perm[hw];
    bool act = ci < CP;
    const __half2* in2 = (const __half2*)in;
    float2 acc = make_float2(0.0f, 0.0f);
    if (act) {
        acc = __half22float2(in2[(long long)node * CP + ci]);
    }
    int r0 = rowptr[node], r1 = rowptr[node + 1];
    int i = r0;
    for (; i + 3 < r1; i += 4) {
        int s0 = csrc[i], s1 = csrc[i + 1], s2 = csrc[i + 2], s3 = csrc[i + 3];
        if (act) {
            float2 v0 = __half22float2(in2[(long long)s0 * CP + ci]);
            float2 v1 = __half22float2(in2[(long long)s1 * CP + ci]);
            float2 v2 = __half22float2(in2[(long long)s2 * CP + ci]);
            float2 v3 = __half22float2(in2[(long long)s3 * CP + ci]);
            acc.x += (v0.x + v1.x) + (v2.x + v3.x);
            acc.y += (v0.y + v1.y) + (v2.y + v3.y);
        }
    }
    for (; i < r1; ++i) {
        int s0 = csrc[i];
        if (act) {
            float2 v0 = __half22float2(in2[(long long)s0 * CP + ci]);
            acc.x += v0.x; acc.y += v0.y;
        }
    }
    float di = dinv[node];
    float2 v = make_float2(-INFINITY, -INFINITY);
    if (act) {
        v.x = di * acc.x + bias[2 * ci];
        v.y = di * acc.y + bias[2 * ci + 1];
    }
    float m = fmaxf(v.x, v.y);
    #pragma unroll
    for (int off = 16; off >= 1; off >>= 1) m = fmaxf(m, __shfl_xor(m, off));
    float e = act ? (expf(v.x - m) + expf(v.y - m)) : 0.0f;
    #pragma unroll
    for (int off = 16; off >= 1; off >>= 1) e += __shfl_xor(e, off);
    float ls = m + logf(e);
    if (act)
        ((float2*)out)[(long long)node * CP + ci] = make_float2(v.x - ls, v.y - ls);
}

// ---------------- MFMA dense linear: out[m,o] = sum_k in[m,k]*W[o,k] -----------
template <int O, int K, bool FP32IN, bool SCALE>
__global__ void __launch_bounds__(256) mfma_lin_k(const void* __restrict__ in_,
                                                  const float* __restrict__ W,
                                                  const float* __restrict__ dinv,
                                                  __half* __restrict__ out, int Mtiles) {
    constexpr int P2 = 52;  // half2 pitch (104 halves = 208 B rows, 16B-aligned)
    __shared__ __half2 wsh[O * P2];
    for (int idx = threadIdx.x; idx < O * (K / 2); idx += 256) {
        int o = idx / (K / 2), kk = idx - o * (K / 2);
        float2 w2 = ((const float2*)W)[o * (K / 2) + kk];
        wsh[o * P2 + kk] = __floats2half2_rn(w2.x, w2.y);
    }
    __syncthreads();
    int wave = (blockIdx.x * 256 + threadIdx.x) >> 6;
    if (wave >= Mtiles) return;
    int lane = threadIdx.x & 63;
    int lm = lane & 15, q = lane >> 4;
    long long m0 = (long long)wave * 16;
    constexpr int NT = (O + 15) / 16;
    f32x4 acc[NT];
    #pragma unroll
    for (int j = 0; j < NT; ++j) acc[j] = (f32x4){0.f, 0.f, 0.f, 0.f};
    const __half* wsp = (const __half*)wsh;
    #pragma unroll
    for (int k0 = 0; k0 < K; k0 += 32) {
        f16x8 a;
        if (FP32IN) {
            const float* xr = (const float*)in_ + (m0 + lm) * K + k0 + q * 8;
            float4 x0 = ((const float4*)xr)[0];
            float4 x1 = ((const float4*)xr)[1];
            a = (f16x8){(_Float16)x0.x, (_Float16)x0.y, (_Float16)x0.z, (_Float16)x0.w,
                        (_Float16)x1.x, (_Float16)x1.y, (_Float16)x1.z, (_Float16)x1.w};
        } else {
            const __half* xr = (const __half*)in_ + (m0 + lm) * K + k0 + q * 8;
            a = *(const f16x8*)xr;
        }
        #pragma unroll
        for (int j = 0; j < NT; ++j) {
            f16x8 b = *(const f16x8*)(wsp + (16 * j + lm) * (2 * P2) + k0 + q * 8);
            acc[j] = __builtin_amdgcn_mfma_f32_16x16x32_f16(a, b, acc[j], 0, 0, 0);
        }
    }
    #pragma unroll
    for (int r = 0; r < 4; ++r) {
        long long m = m0 + q * 4 + r;
        float sc = SCALE ? dinv[m] : 1.0f;
        #pragma unroll
        for (int j = 0; j < NT; ++j) {
            int col = 16 * j + lm;
            if (col < O) out[m * O + col] = __float2half(acc[j][r] * sc);
        }
    }
}

// ---------------- launcher ----------------
static inline int cdiv(long long a, long long b) { return (int)((a + b - 1) / b); }
static inline size_t align256(size_t x) { return (x + 255) & ~(size_t)255; }

extern "C" void kernel_launch(void* const* d_in, const int* in_sizes, int n_in,
                              void* d_out, int out_size, void* d_ws, size_t ws_size,
                              hipStream_t stream) {
    const float* x  = (const float*)d_in[0];
    const void*  ei = d_in[1];
    const float* W0 = (const float*)d_in[2];
    const float* b0 = (const float*)d_in[3];
    const float* W4 = (const float*)d_in[4];
    const float* b4 = (const float*)d_in[5];
    float* out = (float*)d_out;

    const int N = N_NODES, E = N_EDGES;
    const int NB = cdiv(N, 256);  // 196
    char* ws = (char*)d_ws;
    int*    flag   = (int*)ws;     ws += 256;
    int*    deg    = (int*)ws;     ws += align256((size_t)N * 4);
    int*    rowptr = (int*)ws;     ws += align256((size_t)(N + 1) * 4);
    int*    cursor = (int*)ws;     ws += align256((size_t)N * 4);
    int*    part   = (int*)ws;     ws += align256(256 * 4);
    int*    bcnt   = (int*)ws;     ws += align256((size_t)NB * 64 * 4);
    int*    bbase  = (int*)ws;     ws += align256((size_t)NB * 64 * 4);
    int*    tot    = (int*)ws;     ws += align256(64 * 4);
    int*    qtail  = (int*)ws;     ws += align256(8 * 4);
    int*    perm   = (int*)ws;     ws += align256((size_t)N * 4);
    float*  dinv   = (float*)ws;   ws += align256((size_t)N * 4);
    int*    csrc   = (int*)ws;     ws += align256((size_t)E * 4);
    int2*   queue  = (int2*)ws;    ws += align256((size_t)8 * QCAP * 8);
    __half* bufA   = (__half*)ws;  ws += align256((size_t)N * HID_C * 2);
    __half* bufB   = (__half*)ws;  ws += align256((size_t)N * HID_C * 2);
    __half* bufC   = (__half*)ws;  ws += align256((size_t)N * HID_C * 2);

    const int T = 256;
    const int MT = N / 16;             // 3125 MFMA tiles
    const int LB = cdiv(MT, 4);        // mfma_lin blocks (4 waves each)
    const int P64B = cdiv(N, T / 8);   // prop64 blocks (32 groups each)
    const int P40B = cdiv(N, T / 32);  // prop40 blocks (8 HWs each)

    // ---- CSR build (two-phase partition queues) + degree sort ----
    zero_detect_k<<<cdiv(N, T), T, 0, stream>>>(deg, N, qtail, (const unsigned int*)ei, flag);
    bucketA_k<<<cdiv(E, 1024), T, 0, stream>>>(ei, flag, deg, qtail, queue, E);
    scan_p1_k<<<NB, 256, 0, stream>>>(deg, part, N);
    scan_p2_k<<<1, 256, 0, stream>>>(part, NB, rowptr, N);
    scan_p3_k<<<NB, 256, 0, stream>>>(deg, part, rowptr, cursor, dinv, bcnt, N);
    bscanA_k<<<64, 256, 0, stream>>>(bcnt, bbase, tot, NB);
    perm_k<<<NB, 256, 0, stream>>>(deg, bbase, tot, perm, N);
    bucketB_k<<<8 * 64, T, 0, stream>>>(qtail, queue, cursor, csrc);

    // ---- conv0 (SGConv, K=2): linear folded first; output G-space ----
    mfma_lin_k<HID_C, IN_C, true, true><<<LB, 256, 0, stream>>>(x, W0, dinv, bufA, MT);
    prop64_k<false, false, false><<<P64B, T, 0, stream>>>(
        perm, rowptr, csrc, dinv, bufA, nullptr, nullptr, bufB, N);
    prop64_k<false, false, true><<<P64B, T, 0, stream>>>(
        perm, rowptr, csrc, dinv, bufB, nullptr, b0, bufC, N);  // + dinv*b0 -> Gh0

    // ---- conv1..conv3: leaky(APPNP(h)) entirely in G-space, Gh0 = bufC ----
    for (int r = 0; r < 3; ++r) {
        prop64_k<true, false, false><<<P64B, T, 0, stream>>>(
            perm, rowptr, csrc, dinv, bufC, bufC, nullptr, bufB, N);
        // in-place bufC write safe: Gh0[node] read only by the group writing it
        prop64_k<true, true, false><<<P64B, T, 0, stream>>>(
            perm, rowptr, csrc, dinv, bufB, bufC, nullptr, bufC, N);
    }

    // ---- conv4 (SGConv, K=2): G-space lin (no scale), then 2 hops at 40ch ----
    mfma_lin_k<OUT_C, HID_C, false, false><<<LB, 256, 0, stream>>>(bufC, W4, dinv, bufA, MT);
    prop40_k<<<P40B, T, 0, stream>>>(perm, rowptr, csrc, dinv, bufA, bufB, N);
    prop40_softmax_k<<<P40B, T, 0, stream>>>(perm, rowptr, csrc, dinv, bufB, b4, out, N);
}